// Round 1
// baseline (506.958 us; speedup 1.0000x reference)
//
#include <hip/hip_runtime.h>
#include <stdint.h>

#define BN   1024
#define FEATN 512
#define HDIM 256
#define TAUF 5.0f
#define EPSF 1e-8f

typedef __attribute__((ext_vector_type(8))) short short8;
typedef __attribute__((ext_vector_type(4))) float f32x4;

// float -> bf16, round-to-nearest-even, returned as raw short
__device__ __forceinline__ short f2bf(float f) {
  union { float f; unsigned u; } c; c.f = f;
  return (short)((c.u + 0x7fffu + ((c.u >> 16) & 1u)) >> 16);
}

// ---------------- prep: swizzle W1[:512] to bf16 frag order; label softmax ----------------
__global__ __launch_bounds__(256) void prep_kernel(const float* __restrict__ W1,
                                                   const float* __restrict__ lg,
                                                   short* __restrict__ w1swz,
                                                   float* __restrict__ oh) {
  int b = blockIdx.x, t = threadIdx.x;
  if (b < FEATN) {
    int k = b, n = t;
    // B-frag layout: element (k,n) at ((k>>3)*256 + n)*8 + (k&7)
    w1swz[(((k >> 3) * HDIM) + n) * 8 + (k & 7)] = f2bf(W1[k * HDIM + n]);
  } else {
    int i = (b - FEATN) * 256 + t;  // 4 blocks * 256 = 1024
    float l0 = lg[2 * i], l1 = lg[2 * i + 1];
    float m = fmaxf(l0, l1);
    float e0 = expf(l0 - m), e1 = expf(l1 - m);
    float inv = 1.0f / (e0 + e1);
    oh[2 * i] = e0 * inv;
    oh[2 * i + 1] = e1 * inv;
  }
}

// ---------------- main: fused pair-GEMM + gelu + W2-dot + sigmoid ----------------
__global__ __launch_bounds__(256, 4) void gemm_kernel(const float* __restrict__ X,
                                                      const short* __restrict__ w1swz,
                                                      const float* __restrict__ oh,
                                                      const float* __restrict__ W1,
                                                      const float* __restrict__ b1,
                                                      const float* __restrict__ W2,
                                                      const float* __restrict__ b2,
                                                      float* __restrict__ out_hs) {
  // LDS: Xi/Xj rows (f32, stride 516 to stagger banks), A tile in frag order (bf16),
  // score partials, label products.  Total 38656 B -> 4 blocks/CU.
  __shared__ __align__(16) float sXi[8 * 516];
  __shared__ __align__(16) float sXj[8 * 516];
  __shared__ __align__(16) short sA[4 * 64 * 8];
  __shared__ float sScore[64 * 4];
  __shared__ float sLab0[64], sLab1[64];

  const int tid = threadIdx.x;
  const int L = tid & 63;
  const int w = tid >> 6;              // wave id == n-quarter
  const int i0 = blockIdx.y * 8;
  const int j0 = blockIdx.x * 8;

  // ---- stage 16 X rows (8 i-rows, 8 j-rows), 512 f32 each, LDS stride 516 ----
  #pragma unroll
  for (int it = 0; it < 8; ++it) {
    int idx = tid + it * 256;          // 2048 float4 tasks
    int row = idx >> 7;                // 0..15
    int c = idx & 127;                 // float4 column
    int grow = (row < 8) ? (i0 + row) : (j0 + row - 8);
    float4 v = *(const float4*)(X + grow * FEATN + c * 4);
    float* dst = ((row < 8) ? (sXi + row * 516) : (sXj + (row - 8) * 516)) + c * 4;
    *(float4*)dst = v;
  }
  if (tid < 64) {
    int gi = i0 + (tid >> 3), gj = j0 + (tid & 7);
    sLab0[tid] = oh[2 * gi] * oh[2 * gj];
    sLab1[tid] = oh[2 * gi + 1] * oh[2 * gj + 1];
  }

  // ---- A-construct assignment: thread builds the frag MFMA-lane L of subtile sg reads ----
  // m_local = 16*sg + (L&15); pair (ii,jj) = (m>>3, m&7); k-octet = L>>4
  const int sg = tid >> 6;
  const int ii = 2 * sg + ((L & 15) >> 3);
  const int jj = L & 7;
  const int koct = L >> 4;
  const float* cxi = sXi + ii * 516 + koct * 8;
  const float* cxj = sXj + jj * 516 + koct * 8;
  short8* awr = (short8*)(sA + (sg * 64 + L) * 8);

  // B-frag per-lane base (short units): lane L of n-subtile u, k-step kt reads
  // w1swz[ ((kt*4 + (L>>4))*256 + w*64 + u*16 + (L&15)) * 8 ]
  const short* bbase = w1swz + (((L >> 4) * HDIM) + w * 64 + (L & 15)) * 8;

  f32x4 acc[4][4];
  #pragma unroll
  for (int s = 0; s < 4; ++s)
    #pragma unroll
    for (int u = 0; u < 4; ++u) acc[s][u] = (f32x4){0.f, 0.f, 0.f, 0.f};

  __syncthreads();

  #pragma unroll 1
  for (int kt = 0; kt < 16; ++kt) {
    // B fragments straight from L2 (w1swz is 256 KB, L2-resident)
    short8 bfr[4];
    #pragma unroll
    for (int u = 0; u < 4; ++u)
      bfr[u] = *(const short8*)(bbase + kt * 8192 + u * 128);

    // construct this step's A fragment (f32 diff, one rounding to bf16)
    float4 xiA = *(const float4*)(cxi + kt * 32);
    float4 xiB = *(const float4*)(cxi + kt * 32 + 4);
    float4 xjA = *(const float4*)(cxj + kt * 32);
    float4 xjB = *(const float4*)(cxj + kt * 32 + 4);
    union { short8 v; short s[8]; } A;
    A.s[0] = f2bf(fabsf(xiA.x - xjA.x));
    A.s[1] = f2bf(fabsf(xiA.y - xjA.y));
    A.s[2] = f2bf(fabsf(xiA.z - xjA.z));
    A.s[3] = f2bf(fabsf(xiA.w - xjA.w));
    A.s[4] = f2bf(fabsf(xiB.x - xjB.x));
    A.s[5] = f2bf(fabsf(xiB.y - xjB.y));
    A.s[6] = f2bf(fabsf(xiB.z - xjB.z));
    A.s[7] = f2bf(fabsf(xiB.w - xjB.w));
    *awr = A.v;
    __syncthreads();

    short8 afr[4];
    #pragma unroll
    for (int s = 0; s < 4; ++s)
      afr[s] = *(const short8*)(sA + (s * 64 + L) * 8);

    #pragma unroll
    for (int s = 0; s < 4; ++s)
      #pragma unroll
      for (int u = 0; u < 4; ++u)
        acc[s][u] = __builtin_amdgcn_mfma_f32_16x16x32_bf16(afr[s], bfr[u], acc[s][u], 0, 0, 0);
    __syncthreads();
  }

  // ---- epilogue: + label rank-2 term + b1, exact gelu, dot W2, reduce, sigmoid ----
  const int nl = L & 15;
  const int q = L >> 4;
  float w1l0[4], w1l1[4], bb1[4], ww2[4];
  #pragma unroll
  for (int u = 0; u < 4; ++u) {
    int n = w * 64 + u * 16 + nl;
    w1l0[u] = W1[512 * HDIM + n];
    w1l1[u] = W1[513 * HDIM + n];
    bb1[u] = b1[n];
    ww2[u] = W2[n];
  }
  #pragma unroll
  for (int s = 0; s < 4; ++s) {
    #pragma unroll
    for (int r = 0; r < 4; ++r) {
      int m = s * 16 + q * 4 + r;     // C/D: row = quad*4 + reg
      float l0v = sLab0[m], l1v = sLab1[m];
      float v = 0.f;
      #pragma unroll
      for (int u = 0; u < 4; ++u) {
        float e = acc[s][u][r] + l0v * w1l0[u] + l1v * w1l1[u] + bb1[u];
        float g = 0.5f * e * (1.0f + erff(e * 0.70710678118f));
        v += g * ww2[u];
      }
      v += __shfl_xor(v, 1, 64);
      v += __shfl_xor(v, 2, 64);
      v += __shfl_xor(v, 4, 64);
      v += __shfl_xor(v, 8, 64);       // sum over 16 lanes of the quad (16 n each, x4 u)
      if (nl == 0) sScore[m * 4 + w] = v;
    }
  }
  __syncthreads();
  if (tid < 64) {
    float s4 = sScore[tid * 4 + 0] + sScore[tid * 4 + 1] + sScore[tid * 4 + 2] +
               sScore[tid * 4 + 3] + b2[0];
    float hsv = 1.0f / (1.0f + expf(-s4));
    int gi = i0 + (tid >> 3), gj = j0 + (tid & 7);
    out_hs[(size_t)gi * BN + gj] = hsv;
  }
}

// ---------------- row softmax of adj + TAU*log(hs + EPS) ----------------
__global__ __launch_bounds__(256) void softmax_kernel(const float* __restrict__ adj,
                                                      const float* __restrict__ hs,
                                                      float* __restrict__ out) {
  int i = blockIdx.x, t = threadIdx.x;
  __shared__ float redm[4];
  __shared__ float reds[4];
  float l[4];
  float mx = -1e30f;
  #pragma unroll
  for (int k = 0; k < 4; ++k) {
    int j = t + k * 256;
    float lv = adj[(size_t)i * BN + j] + TAUF * logf(hs[(size_t)i * BN + j] + EPSF);
    l[k] = lv;
    mx = fmaxf(mx, lv);
  }
  #pragma unroll
  for (int o = 1; o <= 32; o <<= 1) mx = fmaxf(mx, __shfl_xor(mx, o, 64));
  if ((t & 63) == 0) redm[t >> 6] = mx;
  __syncthreads();
  mx = fmaxf(fmaxf(redm[0], redm[1]), fmaxf(redm[2], redm[3]));
  float ex[4];
  float se = 0.f;
  #pragma unroll
  for (int k = 0; k < 4; ++k) { ex[k] = expf(l[k] - mx); se += ex[k]; }
  #pragma unroll
  for (int o = 1; o <= 32; o <<= 1) se += __shfl_xor(se, o, 64);
  if ((t & 63) == 0) reds[t >> 6] = se;
  __syncthreads();
  se = reds[0] + reds[1] + reds[2] + reds[3];
  float inv = 1.0f / se;
  #pragma unroll
  for (int k = 0; k < 4; ++k) out[(size_t)i * BN + t + k * 256] = ex[k] * inv;
}

extern "C" void kernel_launch(void* const* d_in, const int* in_sizes, int n_in,
                              void* d_out, int out_size, void* d_ws, size_t ws_size,
                              hipStream_t stream) {
  (void)in_sizes; (void)n_in; (void)out_size; (void)ws_size;
  const float* X   = (const float*)d_in[0];
  const float* lg  = (const float*)d_in[1];
  const float* adj = (const float*)d_in[2];
  const float* W1  = (const float*)d_in[3];
  const float* b1  = (const float*)d_in[4];
  const float* W2  = (const float*)d_in[5];
  const float* b2  = (const float*)d_in[6];
  float* out = (float*)d_out;                       // [0,B^2): adj_refined, [B^2,2B^2): h_scores
  short* w1swz = (short*)d_ws;                      // 512*256 bf16 = 256 KB
  float* oh = (float*)((char*)d_ws + FEATN * HDIM * 2);  // 1024*2 f32

  float* out_hs = out + (size_t)BN * BN;

  prep_kernel<<<dim3(FEATN + 4), dim3(256), 0, stream>>>(W1, lg, w1swz, oh);
  gemm_kernel<<<dim3(128, 128), dim3(256), 0, stream>>>(X, w1swz, oh, W1, b1, W2, b2, out_hs);
  softmax_kernel<<<dim3(BN), dim3(256), 0, stream>>>(adj, out_hs, out);
}

// Round 2
// 419.162 us; speedup vs baseline: 1.2095x; 1.2095x over previous
//
#include <hip/hip_runtime.h>
#include <stdint.h>

#define BN   1024
#define FEATN 512
#define HDIM 256
#define TAUF 5.0f
#define EPSF 1e-8f

typedef __attribute__((ext_vector_type(8))) short short8;
typedef __attribute__((ext_vector_type(4))) float f32x4;

// float -> bf16, round-to-nearest-even, returned as raw short (scalar path, prep only)
__device__ __forceinline__ short f2bf(float f) {
  union { float f; unsigned u; } c; c.f = f;
  return (short)((c.u + 0x7fffu + ((c.u >> 16) & 1u)) >> 16);
}

#if defined(__has_builtin)
#if __has_builtin(__builtin_amdgcn_cvt_pk_bf16_f32)
#define HAVE_CVT_PK_BF16 1
#endif
#if __has_builtin(__builtin_amdgcn_rcpf)
#define HAVE_RCPF 1
#endif
#endif

#ifdef HAVE_RCPF
__device__ __forceinline__ float fast_rcp(float x) { return __builtin_amdgcn_rcpf(x); }
#else
__device__ __forceinline__ float fast_rcp(float x) { return 1.0f / x; }
#endif

// pack bf16(a) into low16, bf16(b) into high16 (RTNE)
#ifdef HAVE_CVT_PK_BF16
typedef __attribute__((ext_vector_type(2))) __bf16 bf16x2;
__device__ __forceinline__ int cvt2(float a, float b) {
  bf16x2 r = __builtin_amdgcn_cvt_pk_bf16_f32(a, b);
  int i; __builtin_memcpy(&i, &r, 4); return i;
}
#else
__device__ __forceinline__ int cvt2(float a, float b) {
  unsigned ua = __float_as_uint(a), ub = __float_as_uint(b);
  ua = ua + 0x7fffu + ((ua >> 16) & 1u);
  ub = ub + 0x7fffu + ((ub >> 16) & 1u);
  // v_perm: take high16 of ua (low half) and high16 of ub (high half)
  return (int)__builtin_amdgcn_perm(ub, ua, 0x07060302u);
}
#endif

// tanh-approx gelu == x * sigmoid(1.5957691x + 0.0713548x^3); branchless, 2 transcendentals
__device__ __forceinline__ float gelu_fast(float x) {
  float s = fmaf(x * x, 0.07135481627f, 1.59576912161f) * x;
  float e = __expf(s);
  return x * e * fast_rcp(e + 1.0f);
}

// ---------------- prep: swizzle W1[:512] to bf16 frag order; label softmax ----------------
__global__ __launch_bounds__(256) void prep_kernel(const float* __restrict__ W1,
                                                   const float* __restrict__ lg,
                                                   short* __restrict__ w1swz,
                                                   float* __restrict__ oh) {
  int b = blockIdx.x, t = threadIdx.x;
  if (b < FEATN) {
    int k = b, n = t;
    // B-frag layout: element (k,n) at ((k>>3)*256 + n)*8 + (k&7)
    w1swz[(((k >> 3) * HDIM) + n) * 8 + (k & 7)] = f2bf(W1[k * HDIM + n]);
  } else {
    int i = (b - FEATN) * 256 + t;  // 4 blocks * 256 = 1024
    float l0 = lg[2 * i], l1 = lg[2 * i + 1];
    float m = fmaxf(l0, l1);
    float e0 = expf(l0 - m), e1 = expf(l1 - m);
    float inv = 1.0f / (e0 + e1);
    oh[2 * i] = e0 * inv;
    oh[2 * i + 1] = e1 * inv;
  }
}

// ---------------- main: fused pair-GEMM + gelu + W2-dot + sigmoid ----------------
__global__ __launch_bounds__(256, 4) void gemm_kernel(const float* __restrict__ X,
                                                      const short* __restrict__ w1swz,
                                                      const float* __restrict__ oh,
                                                      const float* __restrict__ W1,
                                                      const float* __restrict__ b1,
                                                      const float* __restrict__ W2,
                                                      const float* __restrict__ b2,
                                                      float* __restrict__ out_hs) {
  __shared__ __align__(16) float sXi[8 * 516];
  __shared__ __align__(16) float sXj[8 * 516];
  __shared__ __align__(16) short sA[4 * 64 * 8];
  __shared__ float sScore[64 * 4];
  __shared__ float sLab0[64], sLab1[64];

  const int tid = threadIdx.x;
  const int L = tid & 63;
  const int w = tid >> 6;              // wave id == n-quarter
  const int i0 = blockIdx.y * 8;
  const int j0 = blockIdx.x * 8;

  // ---- stage 16 X rows (8 i-rows, 8 j-rows), 512 f32 each, LDS stride 516 ----
  #pragma unroll
  for (int it = 0; it < 8; ++it) {
    int idx = tid + it * 256;          // 2048 float4 tasks
    int row = idx >> 7;                // 0..15
    int c = idx & 127;                 // float4 column
    int grow = (row < 8) ? (i0 + row) : (j0 + row - 8);
    float4 v = *(const float4*)(X + grow * FEATN + c * 4);
    float* dst = ((row < 8) ? (sXi + row * 516) : (sXj + (row - 8) * 516)) + c * 4;
    *(float4*)dst = v;
  }
  if (tid < 64) {
    int gi = i0 + (tid >> 3), gj = j0 + (tid & 7);
    sLab0[tid] = oh[2 * gi] * oh[2 * gj];
    sLab1[tid] = oh[2 * gi + 1] * oh[2 * gj + 1];
  }

  // ---- A-construct assignment: thread builds the frag MFMA-lane L of subtile sg reads ----
  const int sg = tid >> 6;
  const int ii = 2 * sg + ((L & 15) >> 3);
  const int jj = L & 7;
  const int koct = L >> 4;
  const float* cxi = sXi + ii * 516 + koct * 8;
  const float* cxj = sXj + jj * 516 + koct * 8;
  short8* awr = (short8*)(sA + (sg * 64 + L) * 8);

  // B-frag per-lane base (short units)
  const short* bbase = w1swz + (((L >> 4) * HDIM) + w * 64 + (L & 15)) * 8;

  f32x4 acc[4][4];
  #pragma unroll
  for (int s = 0; s < 4; ++s)
    #pragma unroll
    for (int u = 0; u < 4; ++u) acc[s][u] = (f32x4){0.f, 0.f, 0.f, 0.f};

  __syncthreads();

  #pragma unroll 1
  for (int kt = 0; kt < 16; ++kt) {
    // B fragments straight from L2 (w1swz is 256 KB, L2-resident)
    short8 bfr[4];
    #pragma unroll
    for (int u = 0; u < 4; ++u)
      bfr[u] = *(const short8*)(bbase + kt * 8192 + u * 128);

    // construct this step's A fragment (f32 diff, one rounding to bf16, packed cvt)
    float4 xiA = *(const float4*)(cxi + kt * 32);
    float4 xiB = *(const float4*)(cxi + kt * 32 + 4);
    float4 xjA = *(const float4*)(cxj + kt * 32);
    float4 xjB = *(const float4*)(cxj + kt * 32 + 4);
    union { int i[4]; short8 v; } A;
    A.i[0] = cvt2(fabsf(xiA.x - xjA.x), fabsf(xiA.y - xjA.y));
    A.i[1] = cvt2(fabsf(xiA.z - xjA.z), fabsf(xiA.w - xjA.w));
    A.i[2] = cvt2(fabsf(xiB.x - xjB.x), fabsf(xiB.y - xjB.y));
    A.i[3] = cvt2(fabsf(xiB.z - xjB.z), fabsf(xiB.w - xjB.w));
    *awr = A.v;
    __syncthreads();

    short8 afr[4];
    #pragma unroll
    for (int s = 0; s < 4; ++s)
      afr[s] = *(const short8*)(sA + (s * 64 + L) * 8);

    #pragma unroll
    for (int s = 0; s < 4; ++s)
      #pragma unroll
      for (int u = 0; u < 4; ++u)
        acc[s][u] = __builtin_amdgcn_mfma_f32_16x16x32_bf16(afr[s], bfr[u], acc[s][u], 0, 0, 0);
    __syncthreads();
  }

  // ---- epilogue: + label rank-2 term + b1, fast gelu, dot W2, reduce, sigmoid ----
  const int nl = L & 15;
  const int q = L >> 4;
  float w1l0[4], w1l1[4], bb1[4], ww2[4];
  #pragma unroll
  for (int u = 0; u < 4; ++u) {
    int n = w * 64 + u * 16 + nl;
    w1l0[u] = W1[512 * HDIM + n];
    w1l1[u] = W1[513 * HDIM + n];
    bb1[u] = b1[n];
    ww2[u] = W2[n];
  }
  #pragma unroll
  for (int s = 0; s < 4; ++s) {
    #pragma unroll
    for (int r = 0; r < 4; ++r) {
      int m = s * 16 + q * 4 + r;     // C/D: row = quad*4 + reg
      float l0v = sLab0[m], l1v = sLab1[m];
      float v = 0.f;
      #pragma unroll
      for (int u = 0; u < 4; ++u) {
        float e = acc[s][u][r] + l0v * w1l0[u] + l1v * w1l1[u] + bb1[u];
        v += gelu_fast(e) * ww2[u];
      }
      v += __shfl_xor(v, 1, 64);
      v += __shfl_xor(v, 2, 64);
      v += __shfl_xor(v, 4, 64);
      v += __shfl_xor(v, 8, 64);       // sum over 16 lanes of the quad
      if (nl == 0) sScore[m * 4 + w] = v;
    }
  }
  __syncthreads();
  if (tid < 64) {
    float s4 = sScore[tid * 4 + 0] + sScore[tid * 4 + 1] + sScore[tid * 4 + 2] +
               sScore[tid * 4 + 3] + b2[0];
    float hsv = 1.0f / (1.0f + expf(-s4));
    int gi = i0 + (tid >> 3), gj = j0 + (tid & 7);
    out_hs[(size_t)gi * BN + gj] = hsv;
  }
}

// ---------------- row softmax of adj + TAU*log(hs + EPS) ----------------
__global__ __launch_bounds__(256) void softmax_kernel(const float* __restrict__ adj,
                                                      const float* __restrict__ hs,
                                                      float* __restrict__ out) {
  int i = blockIdx.x, t = threadIdx.x;
  __shared__ float redm[4];
  __shared__ float reds[4];
  float l[4];
  float mx = -1e30f;
  #pragma unroll
  for (int k = 0; k < 4; ++k) {
    int j = t + k * 256;
    float lv = adj[(size_t)i * BN + j] + TAUF * logf(hs[(size_t)i * BN + j] + EPSF);
    l[k] = lv;
    mx = fmaxf(mx, lv);
  }
  #pragma unroll
  for (int o = 1; o <= 32; o <<= 1) mx = fmaxf(mx, __shfl_xor(mx, o, 64));
  if ((t & 63) == 0) redm[t >> 6] = mx;
  __syncthreads();
  mx = fmaxf(fmaxf(redm[0], redm[1]), fmaxf(redm[2], redm[3]));
  float ex[4];
  float se = 0.f;
  #pragma unroll
  for (int k = 0; k < 4; ++k) { ex[k] = expf(l[k] - mx); se += ex[k]; }
  #pragma unroll
  for (int o = 1; o <= 32; o <<= 1) se += __shfl_xor(se, o, 64);
  if ((t & 63) == 0) reds[t >> 6] = se;
  __syncthreads();
  se = reds[0] + reds[1] + reds[2] + reds[3];
  float inv = 1.0f / se;
  #pragma unroll
  for (int k = 0; k < 4; ++k) out[(size_t)i * BN + t + k * 256] = ex[k] * inv;
}

extern "C" void kernel_launch(void* const* d_in, const int* in_sizes, int n_in,
                              void* d_out, int out_size, void* d_ws, size_t ws_size,
                              hipStream_t stream) {
  (void)in_sizes; (void)n_in; (void)out_size; (void)ws_size;
  const float* X   = (const float*)d_in[0];
  const float* lg  = (const float*)d_in[1];
  const float* adj = (const float*)d_in[2];
  const float* W1  = (const float*)d_in[3];
  const float* b1  = (const float*)d_in[4];
  const float* W2  = (const float*)d_in[5];
  const float* b2  = (const float*)d_in[6];
  float* out = (float*)d_out;                       // [0,B^2): adj_refined, [B^2,2B^2): h_scores
  short* w1swz = (short*)d_ws;                      // 512*256 bf16 = 256 KB
  float* oh = (float*)((char*)d_ws + FEATN * HDIM * 2);  // 1024*2 f32

  float* out_hs = out + (size_t)BN * BN;

  prep_kernel<<<dim3(FEATN + 4), dim3(256), 0, stream>>>(W1, lg, w1swz, oh);
  gemm_kernel<<<dim3(128, 128), dim3(256), 0, stream>>>(X, w1swz, oh, W1, b1, W2, b2, out_hs);
  softmax_kernel<<<dim3(BN), dim3(256), 0, stream>>>(adj, out_hs, out);
}